// Round 7
// baseline (340.086 us; speedup 1.0000x reference)
//
#include <hip/hip_runtime.h>
#include <hip/hip_cooperative_groups.h>
#include <hip/hip_bf16.h>
#include <math.h>

// Problem constants
#define BB 2
#define HH 64
#define WW 64
#define CC 192
#define NH 6
#define HD 32
#define KS 7
#define NPIX 8192
#define SCALE 0.17677669529663687f   // 1/sqrt(32)

typedef __attribute__((ext_vector_type(8))) _Float16 f16x8;
typedef __attribute__((ext_vector_type(2))) _Float16 h2;
typedef __attribute__((ext_vector_type(4))) float    f32x4;

#if defined(__has_builtin) && __has_builtin(__builtin_amdgcn_fdot2)
#define FDOT2(a, b, c) __builtin_amdgcn_fdot2((a), (b), (c), false)
#else
#define FDOT2(a, b, c) fmaf((float)(a)[0], (float)(b)[0], fmaf((float)(a)[1], (float)(b)[1], (c)))
#endif

__device__ __forceinline__ f16x8 cvt8(const float* p) {
    float4 u0 = *(const float4*)p;
    float4 u1 = *(const float4*)(p + 4);
    f16x8 h = {(_Float16)u0.x, (_Float16)u0.y, (_Float16)u0.z, (_Float16)u0.w,
               (_Float16)u1.x, (_Float16)u1.y, (_Float16)u1.z, (_Float16)u1.w};
    return h;
}

// ---------------------------------------------------------------------------
// Phase 1: qkv = x @ w_qkv^T (8192 x 576 x 192). 2304 tiles of 64x32,
// exactly 3 per block (same row-block -> A-fragments reused in registers).
// fp32 inputs converted inline; fp16 output.
// ---------------------------------------------------------------------------
__device__ __forceinline__ void phase_gemm1(int bid, int t,
                                            const float* __restrict__ x,
                                            const float* __restrict__ wq,
                                            _Float16* __restrict__ qkv) {
    const int tm   = bid & 127;          // row tile (64 rows)
    const int g    = bid >> 7;           // 0..5 -> col tiles {g, g+6, g+12}
    const int wave = t >> 6, wr = wave >> 1, wc = wave & 1;
    const int ln   = t & 15, quad = (t & 63) >> 4;

    f16x8 af[2][6];
#pragma unroll
    for (int mi = 0; mi < 2; ++mi) {
        const float* ar = x + (size_t)(tm * 64 + wr * 32 + mi * 16 + ln) * 192;
#pragma unroll
        for (int ks = 0; ks < 6; ++ks)
            af[mi][ks] = cvt8(ar + ks * 32 + quad * 8);
    }

#pragma unroll
    for (int r = 0; r < 3; ++r) {
        const int tn = g + 6 * r;
        const int n  = tn * 32 + wc * 16 + ln;       // output col / wq row
        const float* br = wq + (size_t)n * 192;
        f32x4 acc[2] = {};
#pragma unroll
        for (int ks = 0; ks < 6; ++ks) {
            f16x8 bf = cvt8(br + ks * 32 + quad * 8);
            acc[0] = __builtin_amdgcn_mfma_f32_16x16x32_f16(af[0][ks], bf, acc[0], 0, 0, 0);
            acc[1] = __builtin_amdgcn_mfma_f32_16x16x32_f16(af[1][ks], bf, acc[1], 0, 0, 0);
        }
#pragma unroll
        for (int mi = 0; mi < 2; ++mi)
#pragma unroll
            for (int rg = 0; rg < 4; ++rg)
                qkv[(size_t)(tm * 64 + wr * 32 + mi * 16 + quad * 4 + rg) * 576 + n] =
                    (_Float16)acc[mi][rg];
    }
}

// ---------------------------------------------------------------------------
// Phase 2: neighborhood attention. 768 units = (b, head, qrow), 1 per block.
// Wave w handles window rows {2w, 2w+1} (wave 3: row 6) through a SINGLE
// per-wave row buffer (64 px x 33 u32: k 16 + v 16 + pad; stride 33 -> <=2
// lanes/bank). Buffer reused wave-synchronously (in-order DS). No-max
// softmax (logits O(1), validated R3-R6); plain-sum merge via overlay.
// ---------------------------------------------------------------------------
__device__ __forceinline__ void phase_natten(int bid, int t,
                                             const _Float16* __restrict__ qkv,
                                             const float* __restrict__ rpb,
                                             const float* __restrict__ temperature,
                                             _Float16* __restrict__ outh,
                                             unsigned (*region)[2112],
                                             float* srpb) {
    const int w = t >> 6, j = t & 63;
    const int i = bid & 63, head = (bid >> 6) % NH, b = bid / 384;

    const float tp = temperature[head];
    const float st = SCALE * tp;
    if (t < 169) srpb[t] = rpb[head * 169 + t] * tp;

    const int pix = b * 4096 + i * 64 + j;
    const _Float16* qp = qkv + (size_t)pix * 576 + head * HD;
    h2 qh[16];
    *(uint4*)&qh[0]  = *(const uint4*)(qp);
    *(uint4*)&qh[4]  = *(const uint4*)(qp + 8);
    *(uint4*)&qh[8]  = *(const uint4*)(qp + 16);
    *(uint4*)&qh[12] = *(const uint4*)(qp + 24);
    __syncthreads();   // srpb ready

    const int si = min(max(i - 3, 0), HH - KS);
    const int sj = min(max(j - 3, 0), WW - KS);

    float l = 0.f;
    float acc[HD];
#pragma unroll
    for (int d = 0; d < HD; ++d) acc[d] = 0.f;

    unsigned* reg = region[w];
    const int nrows = (w < 3) ? 2 : 1;
    for (int r = 0; r < nrows; ++r) {
        const int ni = si + 2 * w + r;

        // stage row ni (k 32h + v 32h per px) into the wave's buffer
        const _Float16* rb0 = qkv + (size_t)(b * 4096 + ni * 64) * 576 + 192 + head * HD;
#pragma unroll
        for (int it = 0; it < 8; ++it) {
            const int idx = j + (it << 6);          // 0..511
            const int px = idx >> 3, c = idx & 7;   // c<4: k, c>=4: v
            uint4 d = *(const uint4*)(rb0 + (size_t)px * 576 + (c >> 2) * 192 + (c & 3) * 8);
            *(uint4*)&reg[px * 33 + c * 4] = d;
        }
        // same-wave in-order DS: writes complete before subsequent reads

        const float* rbias = srpb + (ni - i + 6) * 13;
#pragma unroll
        for (int kj = 0; kj < 7; ++kj) {
            const int nj = sj + kj;
            const unsigned* pp = reg + nj * 33;

            h2 kh[16];
            *(uint4*)&kh[0]  = *(const uint4*)(pp + 0);
            *(uint4*)&kh[4]  = *(const uint4*)(pp + 4);
            *(uint4*)&kh[8]  = *(const uint4*)(pp + 8);
            *(uint4*)&kh[12] = *(const uint4*)(pp + 12);

            float d0 = 0.f, d1 = 0.f, d2 = 0.f, d3 = 0.f;
#pragma unroll
            for (int c = 0; c < 4; ++c) {
                d0 = FDOT2(qh[c * 4 + 0], kh[c * 4 + 0], d0);
                d1 = FDOT2(qh[c * 4 + 1], kh[c * 4 + 1], d1);
                d2 = FDOT2(qh[c * 4 + 2], kh[c * 4 + 2], d2);
                d3 = FDOT2(qh[c * 4 + 3], kh[c * 4 + 3], d3);
            }
            const float dot = (d0 + d1) + (d2 + d3);
            const float p = __expf(fmaf(dot, st, rbias[nj - j + 6]));
            l += p;

            h2 vh[16];
            *(uint4*)&vh[0]  = *(const uint4*)(pp + 16);
            *(uint4*)&vh[4]  = *(const uint4*)(pp + 20);
            *(uint4*)&vh[8]  = *(const uint4*)(pp + 24);
            *(uint4*)&vh[12] = *(const uint4*)(pp + 28);
#pragma unroll
            for (int c = 0; c < 16; ++c) {
                acc[2 * c + 0] = fmaf((float)vh[c][0], p, acc[2 * c + 0]);
                acc[2 * c + 1] = fmaf((float)vh[c][1], p, acc[2 * c + 1]);
            }
        }
    }

    // merge wave partials: overlay on each wave's own buffer (j*33 floats)
    if (w > 0) {
        float* mp = (float*)region[w] + j * 33;
#pragma unroll
        for (int d = 0; d < HD; ++d) mp[d] = acc[d];
        mp[32] = l;
    }
    __syncthreads();
    if (w == 0) {
#pragma unroll
        for (int ww = 1; ww < 4; ++ww) {
            const float* mp = (const float*)region[ww] + j * 33;
#pragma unroll
            for (int d = 0; d < HD; ++d) acc[d] += mp[d];
            l += mp[32];
        }
        const float inv = 1.f / l;
        _Float16* op = outh + (size_t)pix * CC + head * HD;
        unsigned o[16];
#pragma unroll
        for (int c = 0; c < 16; ++c) {
            h2 pk;
            pk[0] = (_Float16)(acc[2 * c + 0] * inv);
            pk[1] = (_Float16)(acc[2 * c + 1] * inv);
            o[c] = *(unsigned*)&pk;
        }
        *(uint4*)(op +  0) = *(uint4*)&o[0];
        *(uint4*)(op +  8) = *(uint4*)&o[4];
        *(uint4*)(op + 16) = *(uint4*)&o[8];
        *(uint4*)(op + 24) = *(uint4*)&o[12];
    }
    __syncthreads();   // protect region reuse before phase 3 (none) / exit
}

// ---------------------------------------------------------------------------
// Phase 3: out = attn @ w_proj^T (8192 x 192 x 192). 768 tiles of 64x32,
// exactly 1 per block. A fp16 direct; B fp32 inline-cvt; fp32 out.
// ---------------------------------------------------------------------------
__device__ __forceinline__ void phase_gemm2(int bid, int t,
                                            const _Float16* __restrict__ attn,
                                            const float* __restrict__ wp,
                                            float* __restrict__ out) {
    const int tm = bid / 6, tn = bid % 6;
    const int wave = t >> 6, wr = wave >> 1, wc = wave & 1;
    const int ln = t & 15, quad = (t & 63) >> 4;

    const int n = tn * 32 + wc * 16 + ln;
    const _Float16* ar0 = attn + (size_t)(tm * 64 + wr * 32 + ln) * 192;
    const _Float16* ar1 = attn + (size_t)(tm * 64 + wr * 32 + 16 + ln) * 192;
    const float* br = wp + (size_t)n * 192;

    f32x4 acc[2] = {};
#pragma unroll
    for (int ks = 0; ks < 6; ++ks) {
        const int k0 = ks * 32 + quad * 8;
        f16x8 a0 = *(const f16x8*)(ar0 + k0);
        f16x8 a1 = *(const f16x8*)(ar1 + k0);
        f16x8 bf = cvt8(br + k0);
        acc[0] = __builtin_amdgcn_mfma_f32_16x16x32_f16(a0, bf, acc[0], 0, 0, 0);
        acc[1] = __builtin_amdgcn_mfma_f32_16x16x32_f16(a1, bf, acc[1], 0, 0, 0);
    }
#pragma unroll
    for (int mi = 0; mi < 2; ++mi)
#pragma unroll
        for (int rg = 0; rg < 4; ++rg)
            out[(size_t)(tm * 64 + wr * 32 + mi * 16 + quad * 4 + rg) * 192 + n] = acc[mi][rg];
}

// ---------------------------------------------------------------------------
// Cooperative mega-kernel: all three phases, two grid syncs.
// LDS 34.5 KB, launch_bounds(256,3) -> 3 blocks/CU -> 768 co-resident.
// ---------------------------------------------------------------------------
__global__ __launch_bounds__(256, 3) void mega(const float* __restrict__ x,
                                               const float* __restrict__ wq,
                                               const float* __restrict__ rpb,
                                               const float* __restrict__ temp,
                                               const float* __restrict__ wp,
                                               _Float16* __restrict__ qkv,
                                               _Float16* __restrict__ attn,
                                               float* __restrict__ out) {
    __shared__ unsigned region[4][2112];
    __shared__ float srpb[169];
    const int bid = blockIdx.x, t = threadIdx.x;

    phase_gemm1(bid, t, x, wq, qkv);
    cooperative_groups::this_grid().sync();
    phase_natten(bid, t, qkv, rpb, temp, attn, region, srpb);
    cooperative_groups::this_grid().sync();
    phase_gemm2(bid, t, attn, wp, out);
}

// Fallback plain kernels (used only if cooperative launch is refused)
__global__ __launch_bounds__(256, 3) void p1k(const float* x, const float* wq, _Float16* qkv) {
    phase_gemm1(blockIdx.x, threadIdx.x, x, wq, qkv);
}
__global__ __launch_bounds__(256, 3) void p2k(const _Float16* qkv, const float* rpb,
                                              const float* temp, _Float16* attn) {
    __shared__ unsigned region[4][2112];
    __shared__ float srpb[169];
    phase_natten(blockIdx.x, threadIdx.x, qkv, rpb, temp, attn, region, srpb);
}
__global__ __launch_bounds__(256, 3) void p3k(const _Float16* attn, const float* wp, float* out) {
    phase_gemm2(blockIdx.x, threadIdx.x, attn, wp, out);
}

// ---------------------------------------------------------------------------
extern "C" void kernel_launch(void* const* d_in, const int* in_sizes, int n_in,
                              void* d_out, int out_size, void* d_ws, size_t ws_size,
                              hipStream_t stream) {
    const float* x           = (const float*)d_in[0];
    const float* w_qkv       = (const float*)d_in[1];
    const float* rpb         = (const float*)d_in[2];
    const float* temperature = (const float*)d_in[3];
    const float* w_proj      = (const float*)d_in[4];
    float* out = (float*)d_out;

    _Float16* qkv_h  = (_Float16*)d_ws;
    _Float16* attn_h = qkv_h + (size_t)NPIX * 3 * CC;

    void* args[8] = {(void*)&x, (void*)&w_qkv, (void*)&rpb, (void*)&temperature,
                     (void*)&w_proj, (void*)&qkv_h, (void*)&attn_h, (void*)&out};
    hipError_t e = hipLaunchCooperativeKernel((const void*)mega, dim3(768), dim3(256),
                                              (void**)args, 0, stream);
    if (e != hipSuccess) {
        p1k<<<dim3(768), 256, 0, stream>>>(x, w_qkv, qkv_h);
        p2k<<<dim3(768), 256, 0, stream>>>(qkv_h, rpb, temperature, attn_h);
        p3k<<<dim3(768), 256, 0, stream>>>(attn_h, w_proj, out);
    }
}

// Round 8
// 143.768 us; speedup vs baseline: 2.3655x; 2.3655x over previous
//
#include <hip/hip_runtime.h>
#include <hip/hip_bf16.h>
#include <math.h>

// Problem constants
#define BB 2
#define HH 64
#define WW 64
#define CC 192
#define NH 6
#define HD 32
#define KS 7
#define NPIX 8192
#define SCALE 0.17677669529663687f   // 1/sqrt(32)

typedef __attribute__((ext_vector_type(8))) _Float16 f16x8;
typedef __attribute__((ext_vector_type(2))) _Float16 h2;
typedef __attribute__((ext_vector_type(4))) float    f32x4;

#if defined(__has_builtin) && __has_builtin(__builtin_amdgcn_fdot2)
#define FDOT2(a, b, c) __builtin_amdgcn_fdot2((a), (b), (c), false)
#else
#define FDOT2(a, b, c) fmaf((float)(a)[0], (float)(b)[0], fmaf((float)(a)[1], (float)(b)[1], (c)))
#endif

// qkv workspace layout: [type q/k/v][head][pix][32] halves (head-major planes)
#define PLANE ((size_t)NPIX * 32)    // halves per (type,head) plane

__device__ __forceinline__ f16x8 cvt8(const float* p) {
    float4 u0 = *(const float4*)p;
    float4 u1 = *(const float4*)(p + 4);
    f16x8 h = {(_Float16)u0.x, (_Float16)u0.y, (_Float16)u0.z, (_Float16)u0.w,
               (_Float16)u1.x, (_Float16)u1.y, (_Float16)u1.z, (_Float16)u1.w};
    return h;
}

// ---------------------------------------------------------------------------
// Kernel 1: qkv projection (8192 x 576 x 192), fp32 in -> fp16 head-major out.
// 768 blocks: tm = row tile (64 px), g = head. Each block computes tiles
// r=0,1,2 = (q,k,v) of head g — A-fragments reused in registers across r.
// Column tile (g+6r)*32 maps exactly to (type r, head g, ch 0..31).
// ---------------------------------------------------------------------------
__global__ __launch_bounds__(256) void qkv_gemm(const float* __restrict__ x,
                                                const float* __restrict__ wq,
                                                _Float16* __restrict__ qkv) {
    const int tm   = blockIdx.x & 127;
    const int g    = blockIdx.x >> 7;            // head
    const int t    = threadIdx.x;
    const int wave = t >> 6, wr = wave >> 1, wc = wave & 1;
    const int ln   = t & 15, quad = (t & 63) >> 4;

    f16x8 af[2][6];
#pragma unroll
    for (int mi = 0; mi < 2; ++mi) {
        const float* ar = x + (size_t)(tm * 64 + wr * 32 + mi * 16 + ln) * 192;
#pragma unroll
        for (int ks = 0; ks < 6; ++ks)
            af[mi][ks] = cvt8(ar + ks * 32 + quad * 8);
    }

    const int c = wc * 16 + ln;                  // channel 0..31
#pragma unroll
    for (int r = 0; r < 3; ++r) {                // type: q, k, v
        const int nfull = (g + 6 * r) * 32 + c;  // w_qkv row
        const float* br = wq + (size_t)nfull * 192;
        f32x4 acc[2] = {};
#pragma unroll
        for (int ks = 0; ks < 6; ++ks) {
            f16x8 bf = cvt8(br + ks * 32 + quad * 8);
            acc[0] = __builtin_amdgcn_mfma_f32_16x16x32_f16(af[0][ks], bf, acc[0], 0, 0, 0);
            acc[1] = __builtin_amdgcn_mfma_f32_16x16x32_f16(af[1][ks], bf, acc[1], 0, 0, 0);
        }
        _Float16* base = qkv + (size_t)(r * NH + g) * PLANE + c;
#pragma unroll
        for (int mi = 0; mi < 2; ++mi)
#pragma unroll
            for (int rg = 0; rg < 4; ++rg) {
                const int pix = tm * 64 + wr * 32 + mi * 16 + quad * 4 + rg;
                base[(size_t)pix * 32] = (_Float16)acc[mi][rg];
            }
    }
}

// ---------------------------------------------------------------------------
// Kernel 2: neighborhood attention. 768 blocks = (b, head, qrow), 4 waves.
// Head-major qkv: q-load and k/v staging are perfectly coalesced (each
// window row is one contiguous 4 KB run). Wave w stages rows {2w,2w+1}
// (wave 3: row 6) through its own 64px x 33-u32 buffer (k u32 0..15,
// v 16..31; stride 33 -> structural-minimum banking, verified conflict-free
// in R1/R2 counters). No-max softmax (logits O(1), validated R3-R6);
// plain-sum cross-wave merge via overlay. LDS 34.5 KB -> 4 blocks/CU.
// ---------------------------------------------------------------------------
__global__ __launch_bounds__(256) void natten_v5(const _Float16* __restrict__ qkv,
                                                 const float* __restrict__ rpb,
                                                 const float* __restrict__ temperature,
                                                 _Float16* __restrict__ outh) {
    const int t = threadIdx.x;
    const int w = t >> 6, j = t & 63;
    const int i = blockIdx.x & 63;
    const int head = (blockIdx.x >> 6) % NH;
    const int b = blockIdx.x / 384;

    __shared__ unsigned region[4][2112];
    __shared__ float srpb[169];

    const float tp = temperature[head];
    const float st = SCALE * tp;
    if (t < 169) srpb[t] = rpb[head * 169 + t] * tp;

    const int pix = b * 4096 + i * 64 + j;
    const _Float16* qp = qkv + (size_t)head * PLANE + (size_t)pix * 32;
    h2 qh[16];
    *(uint4*)&qh[0]  = *(const uint4*)(qp);       // lane-contiguous: 1KB/inst
    *(uint4*)&qh[4]  = *(const uint4*)(qp + 8);
    *(uint4*)&qh[8]  = *(const uint4*)(qp + 16);
    *(uint4*)&qh[12] = *(const uint4*)(qp + 24);
    __syncthreads();   // srpb ready

    const int si = min(max(i - 3, 0), HH - KS);
    const int sj = min(max(j - 3, 0), WW - KS);

    float l = 0.f;
    float acc[HD];
#pragma unroll
    for (int d = 0; d < HD; ++d) acc[d] = 0.f;

    unsigned* reg = region[w];
    const int nrows = (w < 3) ? 2 : 1;
    for (int r = 0; r < nrows; ++r) {
        const int ni = si + 2 * w + r;
        const size_t rowpix = (size_t)(b * 4096 + ni * 64) * 32;
        const _Float16* kb = qkv + (size_t)(NH + head) * PLANE + rowpix;
        const _Float16* vb = qkv + (size_t)(2 * NH + head) * PLANE + rowpix;

        // stage row ni: 8 fully-coalesced uint4 loads (4 k + 4 v)
#pragma unroll
        for (int it = 0; it < 8; ++it) {
            const int q4 = j + ((it & 3) << 6);        // uint4 idx in 4KB row
            const _Float16* src = (it < 4 ? kb : vb) + q4 * 8;
            uint4 d = *(const uint4*)src;
            const int px = q4 >> 2, sub = q4 & 3;
            *(uint4*)&reg[px * 33 + (it < 4 ? 0 : 16) + sub * 4] = d;
        }
        // same-wave in-order DS: writes complete before subsequent reads

        const float* rbias = srpb + (ni - i + 6) * 13;
#pragma unroll
        for (int kj = 0; kj < 7; ++kj) {
            const int nj = sj + kj;
            const unsigned* pp = reg + nj * 33;

            h2 kh[16];
            *(uint4*)&kh[0]  = *(const uint4*)(pp + 0);
            *(uint4*)&kh[4]  = *(const uint4*)(pp + 4);
            *(uint4*)&kh[8]  = *(const uint4*)(pp + 8);
            *(uint4*)&kh[12] = *(const uint4*)(pp + 12);

            float d0 = 0.f, d1 = 0.f, d2 = 0.f, d3 = 0.f;
#pragma unroll
            for (int cc = 0; cc < 4; ++cc) {
                d0 = FDOT2(qh[cc * 4 + 0], kh[cc * 4 + 0], d0);
                d1 = FDOT2(qh[cc * 4 + 1], kh[cc * 4 + 1], d1);
                d2 = FDOT2(qh[cc * 4 + 2], kh[cc * 4 + 2], d2);
                d3 = FDOT2(qh[cc * 4 + 3], kh[cc * 4 + 3], d3);
            }
            const float dot = (d0 + d1) + (d2 + d3);
            const float p = __expf(fmaf(dot, st, rbias[nj - j + 6]));
            l += p;

            h2 vh[16];
            *(uint4*)&vh[0]  = *(const uint4*)(pp + 16);
            *(uint4*)&vh[4]  = *(const uint4*)(pp + 20);
            *(uint4*)&vh[8]  = *(const uint4*)(pp + 24);
            *(uint4*)&vh[12] = *(const uint4*)(pp + 28);
#pragma unroll
            for (int cc = 0; cc < 16; ++cc) {
                acc[2 * cc + 0] = fmaf((float)vh[cc][0], p, acc[2 * cc + 0]);
                acc[2 * cc + 1] = fmaf((float)vh[cc][1], p, acc[2 * cc + 1]);
            }
        }
    }

    // merge wave partials (plain sums; overlay on each wave's own buffer)
    if (w > 0) {
        float* mp = (float*)region[w] + j * 33;
#pragma unroll
        for (int d = 0; d < HD; ++d) mp[d] = acc[d];
        mp[32] = l;
    }
    __syncthreads();
    if (w == 0) {
#pragma unroll
        for (int ww = 1; ww < 4; ++ww) {
            const float* mp = (const float*)region[ww] + j * 33;
#pragma unroll
            for (int d = 0; d < HD; ++d) acc[d] += mp[d];
            l += mp[32];
        }
        const float inv = 1.f / l;
        _Float16* op = outh + (size_t)pix * CC + head * HD;   // [pix][192]
        unsigned o[16];
#pragma unroll
        for (int cc = 0; cc < 16; ++cc) {
            h2 pk;
            pk[0] = (_Float16)(acc[2 * cc + 0] * inv);
            pk[1] = (_Float16)(acc[2 * cc + 1] * inv);
            o[cc] = *(unsigned*)&pk;
        }
        *(uint4*)(op +  0) = *(uint4*)&o[0];
        *(uint4*)(op +  8) = *(uint4*)&o[4];
        *(uint4*)(op + 16) = *(uint4*)&o[8];
        *(uint4*)(op + 24) = *(uint4*)&o[12];
    }
}

// ---------------------------------------------------------------------------
// Kernel 3: out = attn @ w_proj^T (8192 x 192 x 192). 768 blocks of one
// 64x32 tile. A fp16 direct; B fp32 inline-cvt; fp32 out.
// ---------------------------------------------------------------------------
__global__ __launch_bounds__(256) void proj_gemm(const _Float16* __restrict__ attn,
                                                 const float* __restrict__ wp,
                                                 float* __restrict__ out) {
    const int bid = blockIdx.x, t = threadIdx.x;
    const int tm = bid / 6, tn = bid % 6;
    const int wave = t >> 6, wr = wave >> 1, wc = wave & 1;
    const int ln = t & 15, quad = (t & 63) >> 4;

    const int n = tn * 32 + wc * 16 + ln;
    const _Float16* ar0 = attn + (size_t)(tm * 64 + wr * 32 + ln) * 192;
    const _Float16* ar1 = attn + (size_t)(tm * 64 + wr * 32 + 16 + ln) * 192;
    const float* br = wp + (size_t)n * 192;

    f32x4 acc[2] = {};
#pragma unroll
    for (int ks = 0; ks < 6; ++ks) {
        const int k0 = ks * 32 + quad * 8;
        f16x8 a0 = *(const f16x8*)(ar0 + k0);
        f16x8 a1 = *(const f16x8*)(ar1 + k0);
        f16x8 bf = cvt8(br + k0);
        acc[0] = __builtin_amdgcn_mfma_f32_16x16x32_f16(a0, bf, acc[0], 0, 0, 0);
        acc[1] = __builtin_amdgcn_mfma_f32_16x16x32_f16(a1, bf, acc[1], 0, 0, 0);
    }
#pragma unroll
    for (int mi = 0; mi < 2; ++mi)
#pragma unroll
        for (int rg = 0; rg < 4; ++rg)
            out[(size_t)(tm * 64 + wr * 32 + mi * 16 + quad * 4 + rg) * 192 + n] = acc[mi][rg];
}

// ---------------------------------------------------------------------------
extern "C" void kernel_launch(void* const* d_in, const int* in_sizes, int n_in,
                              void* d_out, int out_size, void* d_ws, size_t ws_size,
                              hipStream_t stream) {
    const float* x           = (const float*)d_in[0];
    const float* w_qkv       = (const float*)d_in[1];
    const float* rpb         = (const float*)d_in[2];
    const float* temperature = (const float*)d_in[3];
    const float* w_proj      = (const float*)d_in[4];
    float* out = (float*)d_out;

    _Float16* qkv_h  = (_Float16*)d_ws;                 // 3*6*8192*32 halves
    _Float16* attn_h = qkv_h + (size_t)NPIX * 3 * CC;   // 8192*192 halves

    qkv_gemm<<<dim3(768), 256, 0, stream>>>(x, w_qkv, qkv_h);
    natten_v5<<<dim3(768), 256, 0, stream>>>(qkv_h, rpb, temperature, attn_h);
    proj_gemm<<<dim3(768), 256, 0, stream>>>(attn_h, w_proj, out);
}